// Round 1
// baseline (309.779 us; speedup 1.0000x reference)
//
#include <hip/hip_runtime.h>
#include <math.h>

#define NV 6890
#define N3 20670      // NV*3
#define NJNT 24
#define NBETA 10
#define NPF 207
#define NJO 19
#define NBATCH 512
#define BT 64         // batch tile for posedirs GEMM

__constant__ int d_par[NJNT] = {0,0,0,0,1,2,3,4,5,6,7,8,9,9,9,12,13,14,16,17,18,19,20,21};

// Transpose lbs_weights (V,24)->(24,V) and joint_regressor (V,19)->(19,V) for coalesced reads.
__global__ void k_transpose(const float* __restrict__ lbs, const float* __restrict__ jr,
                            float* __restrict__ lbsT, float* __restrict__ jrT) {
  int idx = blockIdx.x * 256 + threadIdx.x;
  if (idx < NV * NJNT) { int k = idx / NV, v = idx - k * NV; lbsT[idx] = lbs[v * NJNT + k]; }
  if (idx < NV * NJO)  { int k = idx / NV, v = idx - k * NV; jrT[idx]  = jr[v * NJO + k]; }
}

// v_shaped[b,n] = v_template[n] + sum_k beta[b,k]*shapedirs[k,n]
__global__ void k_vshaped(const float* __restrict__ beta, const float* __restrict__ sdirs,
                          const float* __restrict__ vtmpl, float* __restrict__ vs) {
  int n = blockIdx.x * 256 + threadIdx.x;
  if (n >= N3) return;
  int b = blockIdx.y;
  float acc = vtmpl[n];
  const float* bb = beta + b * NBETA;
#pragma unroll
  for (int k = 0; k < NBETA; ++k) acc += bb[k] * sdirs[k * N3 + n];
  vs[(size_t)b * N3 + n] = acc;
}

// Rodrigues per (b): writes Rs[b][24][9] and transposed pose_feature pfT[207][512]
__global__ void k_rod(const float* __restrict__ theta, float* __restrict__ Rs,
                      float* __restrict__ pfT) {
  int b = blockIdx.x * 64 + threadIdx.x;
  if (b >= NBATCH) return;
  for (int j = 0; j < NJNT; ++j) {
    float a0 = theta[b * 72 + j * 3 + 0];
    float a1 = theta[b * 72 + j * 3 + 1];
    float a2 = theta[b * 72 + j * 3 + 2];
    float e0 = a0 + 1e-8f, e1 = a1 + 1e-8f, e2 = a2 + 1e-8f;
    float ang = sqrtf(e0 * e0 + e1 * e1 + e2 * e2);
    float inv = 1.0f / ang;
    float h = 0.5f * ang;
    float w = cosf(h), s = sinf(h);
    float x = a0 * inv * s, y = a1 * inv * s, z = a2 * inv * s;
    float R[9];
    R[0] = w*w + x*x - y*y - z*z; R[1] = 2.f*(x*y - w*z); R[2] = 2.f*(x*z + w*y);
    R[3] = 2.f*(x*y + w*z); R[4] = w*w - x*x + y*y - z*z; R[5] = 2.f*(y*z - w*x);
    R[6] = 2.f*(x*z - w*y); R[7] = 2.f*(y*z + w*x); R[8] = w*w - x*x - y*y + z*z;
#pragma unroll
    for (int r = 0; r < 9; ++r) Rs[b * 216 + j * 9 + r] = R[r];
    if (j >= 1) {
#pragma unroll
      for (int r = 0; r < 9; ++r) {
        float pv = R[r] - ((r % 4 == 0) ? 1.0f : 0.0f);  // subtract eye(3)
        pfT[((j - 1) * 9 + r) * NBATCH + b] = pv;
      }
    }
  }
}

// J[b,j,c] = sum_v v_shaped[b,v,c] * J_regressor[v,j]; one block per b
__global__ void __launch_bounds__(256) k_J(const float* __restrict__ vs,
                                           const float* __restrict__ Jreg,
                                           float* __restrict__ Jout) {
  int b = blockIdx.x, tid = threadIdx.x;
  float acc[NJNT * 3];
#pragma unroll
  for (int i = 0; i < NJNT * 3; ++i) acc[i] = 0.f;
  for (int v = tid; v < NV; v += 256) {
    float x = vs[(size_t)b * N3 + v * 3 + 0];
    float y = vs[(size_t)b * N3 + v * 3 + 1];
    float z = vs[(size_t)b * N3 + v * 3 + 2];
    const float4* jr4 = (const float4*)(Jreg + v * NJNT);
#pragma unroll
    for (int q = 0; q < 6; ++q) {
      float4 w4 = jr4[q];
      float wv[4] = {w4.x, w4.y, w4.z, w4.w};
#pragma unroll
      for (int m = 0; m < 4; ++m) {
        int j = q * 4 + m;
        acc[j * 3 + 0] += wv[m] * x;
        acc[j * 3 + 1] += wv[m] * y;
        acc[j * 3 + 2] += wv[m] * z;
      }
    }
  }
  __shared__ float red[4][NJNT * 3];
  int lane = tid & 63, wid = tid >> 6;
#pragma unroll
  for (int i = 0; i < NJNT * 3; ++i) {
    float v = acc[i];
    v += __shfl_xor(v, 1);  v += __shfl_xor(v, 2);  v += __shfl_xor(v, 4);
    v += __shfl_xor(v, 8);  v += __shfl_xor(v, 16); v += __shfl_xor(v, 32);
    if (lane == 0) red[wid][i] = v;
  }
  __syncthreads();
  if (tid < NJNT * 3)
    Jout[b * NJNT * 3 + tid] = red[0][tid] + red[1][tid] + red[2][tid] + red[3][tid];
}

// Kinematic chain per batch: A[b][24][12] (rows 0..2 of the relative 4x4s)
__global__ void k_chain(const float* __restrict__ Rs, const float* __restrict__ Jin,
                        float* __restrict__ A) {
  int b = blockIdx.x * 64 + threadIdx.x;
  if (b >= NBATCH) return;
  const float* Jb = Jin + b * 72;
  const float* Rb = Rs + b * 216;
  float* Ab = A + b * 288;
  // joint 0: [R0 | J0]
#pragma unroll
  for (int r = 0; r < 3; ++r) {
#pragma unroll
    for (int c = 0; c < 3; ++c) Ab[r * 4 + c] = Rb[r * 3 + c];
    Ab[r * 4 + 3] = Jb[r];
  }
  for (int i = 1; i < NJNT; ++i) {
    int p = d_par[i];
    const float* P = Ab + p * 12;
    const float* R = Rb + i * 9;
    float t0 = Jb[i * 3 + 0] - Jb[p * 3 + 0];
    float t1 = Jb[i * 3 + 1] - Jb[p * 3 + 1];
    float t2 = Jb[i * 3 + 2] - Jb[p * 3 + 2];
    float* O = Ab + i * 12;
#pragma unroll
    for (int r = 0; r < 3; ++r) {
      float p0 = P[r * 4 + 0], p1 = P[r * 4 + 1], p2 = P[r * 4 + 2], p3 = P[r * 4 + 3];
#pragma unroll
      for (int c = 0; c < 3; ++c)
        O[r * 4 + c] = p0 * R[0 + c] + p1 * R[3 + c] + p2 * R[6 + c];
      O[r * 4 + 3] = p0 * t0 + p1 * t1 + p2 * t2 + p3;
    }
  }
  // A_rel: translation col -= rot @ J_i
  for (int i = 0; i < NJNT; ++i) {
    float jx = Jb[i * 3 + 0], jy = Jb[i * 3 + 1], jz = Jb[i * 3 + 2];
    float* O = Ab + i * 12;
#pragma unroll
    for (int r = 0; r < 3; ++r)
      O[r * 4 + 3] -= O[r * 4 + 0] * jx + O[r * 4 + 1] * jy + O[r * 4 + 2] * jz;
  }
}

// v_posed[b,n] = v_shaped[b,n] + sum_k pf[b,k]*posedirs[k,n]
// Each thread: 1 column n, BT batches. pfT reads are wave-uniform -> s_load.
__global__ void __launch_bounds__(256) k_vposed(const float* __restrict__ pfT,
                                                const float* __restrict__ pdirs,
                                                const float* __restrict__ vs,
                                                float* __restrict__ vp) {
  int n = blockIdx.x * 256 + threadIdx.x;
  if (n >= N3) return;
  int b0 = blockIdx.y * BT;
  float acc[BT];
#pragma unroll
  for (int i = 0; i < BT; ++i) acc[i] = 0.f;
  for (int k = 0; k < NPF; ++k) {
    float pd = pdirs[(size_t)k * N3 + n];
    const float* pfk = pfT + k * NBATCH + b0;  // uniform across lanes
#pragma unroll
    for (int i = 0; i < BT; ++i) acc[i] += pfk[i] * pd;
  }
#pragma unroll
  for (int i = 0; i < BT; ++i)
    vp[(size_t)(b0 + i) * N3 + n] = acc[i] + vs[(size_t)(b0 + i) * N3 + n];
}

// Fused LBS + vertex transform + joint regression; one block per b
__global__ void __launch_bounds__(256) k_lbs(const float* __restrict__ vp,
                                             const float* __restrict__ lbsT,
                                             const float* __restrict__ jrT,
                                             const float* __restrict__ A,
                                             float* __restrict__ out) {
  int b = blockIdx.x, tid = threadIdx.x;
  const float* Ab = A + b * 288;
  float acc[NJO * 3];
#pragma unroll
  for (int i = 0; i < NJO * 3; ++i) acc[i] = 0.f;
  for (int v = tid; v < NV; v += 256) {
    float x = vp[(size_t)b * N3 + v * 3 + 0];
    float y = vp[(size_t)b * N3 + v * 3 + 1];
    float z = vp[(size_t)b * N3 + v * 3 + 2];
    float vx = 0.f, vy = 0.f, vz = 0.f;
#pragma unroll
    for (int k = 0; k < NJNT; ++k) {
      float w = lbsT[k * NV + v];
      float4 A0 = *(const float4*)(Ab + k * 12 + 0);  // uniform -> s_load
      float4 A1 = *(const float4*)(Ab + k * 12 + 4);
      float4 A2 = *(const float4*)(Ab + k * 12 + 8);
      vx += w * (A0.x * x + A0.y * y + A0.z * z + A0.w);
      vy += w * (A1.x * x + A1.y * y + A1.z * z + A1.w);
      vz += w * (A2.x * x + A2.y * y + A2.z * z + A2.w);
    }
#pragma unroll
    for (int j = 0; j < NJO; ++j) {
      float w = jrT[j * NV + v];
      acc[j * 3 + 0] += w * vx;
      acc[j * 3 + 1] += w * vy;
      acc[j * 3 + 2] += w * vz;
    }
  }
  __shared__ float red[4][NJO * 3];
  int lane = tid & 63, wid = tid >> 6;
#pragma unroll
  for (int i = 0; i < NJO * 3; ++i) {
    float v = acc[i];
    v += __shfl_xor(v, 1);  v += __shfl_xor(v, 2);  v += __shfl_xor(v, 4);
    v += __shfl_xor(v, 8);  v += __shfl_xor(v, 16); v += __shfl_xor(v, 32);
    if (lane == 0) red[wid][i] = v;
  }
  __syncthreads();
  if (tid < NJO * 3)
    out[b * NJO * 3 + tid] = red[0][tid] + red[1][tid] + red[2][tid] + red[3][tid];
}

extern "C" void kernel_launch(void* const* d_in, const int* in_sizes, int n_in,
                              void* d_out, int out_size, void* d_ws, size_t ws_size,
                              hipStream_t stream) {
  const float* beta  = (const float*)d_in[0];
  const float* theta = (const float*)d_in[1];
  const float* vtmpl = (const float*)d_in[2];
  const float* sdirs = (const float*)d_in[3];
  const float* Jreg  = (const float*)d_in[4];
  const float* pdirs = (const float*)d_in[5];
  const float* lbs   = (const float*)d_in[6];
  const float* jreg2 = (const float*)d_in[7];
  float* out = (float*)d_out;

  float* ws   = (float*)d_ws;
  float* vs   = ws;                                  // 512*20670
  float* vp   = vs   + (size_t)NBATCH * N3;          // 512*20670
  float* Rs   = vp   + (size_t)NBATCH * N3;          // 512*216
  float* pfT  = Rs   + (size_t)NBATCH * 216;         // 207*512
  float* Jout = pfT  + (size_t)NPF * NBATCH;         // 512*72
  float* A    = Jout + (size_t)NBATCH * 72;          // 512*288
  float* lbsT = A    + (size_t)NBATCH * 288;         // 24*6890
  float* jrT  = lbsT + (size_t)NJNT * NV;            // 19*6890

  k_transpose<<<dim3((NV * NJNT + 255) / 256), 256, 0, stream>>>(lbs, jreg2, lbsT, jrT);
  k_vshaped<<<dim3((N3 + 255) / 256, NBATCH), 256, 0, stream>>>(beta, sdirs, vtmpl, vs);
  k_rod<<<dim3(8), 64, 0, stream>>>(theta, Rs, pfT);
  k_J<<<dim3(NBATCH), 256, 0, stream>>>(vs, Jreg, Jout);
  k_chain<<<dim3(8), 64, 0, stream>>>(Rs, Jout, A);
  k_vposed<<<dim3((N3 + 255) / 256, NBATCH / BT), 256, 0, stream>>>(pfT, pdirs, vs, vp);
  k_lbs<<<dim3(NBATCH), 256, 0, stream>>>(vp, lbsT, jrT, A, out);
}

// Round 2
// 271.023 us; speedup vs baseline: 1.1430x; 1.1430x over previous
//
#include <hip/hip_runtime.h>
#include <math.h>

#define NV 6890
#define N3 20670      // NV*3
#define NJNT 24
#define NBETA 10
#define NPF 207
#define NJO 19
#define NBATCH 512
#define BT 32         // batch tile for posedirs GEMM
#define VS 2          // vertex splits in k_lbs
#define VCHUNK 3445   // NV / VS

__constant__ int d_par[NJNT] = {0,0,0,0,1,2,3,4,5,6,7,8,9,9,9,12,13,14,16,17,18,19,20,21};

// Transpose lbs_weights (V,24)->(24,V), joint_regressor (V,19)->(19,V), beta (512,10)->(10,512)
__global__ void k_transpose(const float* __restrict__ lbs, const float* __restrict__ jr,
                            const float* __restrict__ beta,
                            float* __restrict__ lbsT, float* __restrict__ jrT,
                            float* __restrict__ betaT) {
  int idx = blockIdx.x * 256 + threadIdx.x;
  if (idx < NV * NJNT) { int k = idx / NV, v = idx - k * NV; lbsT[idx] = lbs[v * NJNT + k]; }
  if (idx < NV * NJO)  { int k = idx / NV, v = idx - k * NV; jrT[idx]  = jr[v * NJO + k]; }
  if (idx < NBATCH * NBETA) { int k = idx / NBATCH, b = idx - k * NBATCH; betaT[idx] = beta[b * NBETA + k]; }
}

// SJ[k][j][c] = sum_v Jreg[v,j] * sdirs[k,(v,c)]  for k<10; k==10 row uses v_template (-> J0)
__global__ void __launch_bounds__(256) k_SJ(const float* __restrict__ Jreg,
                                            const float* __restrict__ sdirs,
                                            const float* __restrict__ vtmpl,
                                            float* __restrict__ SJ) {
  int j = blockIdx.x;   // 0..23
  int k = blockIdx.y;   // 0..10
  int tid = threadIdx.x;
  const float* src = (k < NBETA) ? (sdirs + (size_t)k * N3) : vtmpl;
  float a0 = 0.f, a1 = 0.f, a2 = 0.f;
  for (int v = tid; v < NV; v += 256) {
    float w = Jreg[v * NJNT + j];
    a0 += w * src[v * 3 + 0];
    a1 += w * src[v * 3 + 1];
    a2 += w * src[v * 3 + 2];
  }
  __shared__ float red[4][3];
  int lane = tid & 63, wid = tid >> 6;
#pragma unroll
  for (int s = 1; s < 64; s <<= 1) {
    a0 += __shfl_xor(a0, s); a1 += __shfl_xor(a1, s); a2 += __shfl_xor(a2, s);
  }
  if (lane == 0) { red[wid][0] = a0; red[wid][1] = a1; red[wid][2] = a2; }
  __syncthreads();
  if (tid == 0) {
    float* o = SJ + (k * NJNT + j) * 3;
    o[0] = red[0][0] + red[1][0] + red[2][0] + red[3][0];
    o[1] = red[0][1] + red[1][1] + red[2][1] + red[3][1];
    o[2] = red[0][2] + red[1][2] + red[2][2] + red[3][2];
  }
}

// J[b][j][c] = SJ[10][j][c] + sum_k beta[b,k]*SJ[k][j][c]
__global__ void k_Jsmall(const float* __restrict__ beta, const float* __restrict__ SJ,
                         float* __restrict__ J) {
  int idx = blockIdx.x * 256 + threadIdx.x;
  if (idx >= NBATCH * 72) return;
  int b = idx / 72, r = idx - b * 72;
  float acc = SJ[NBETA * 72 + r];
  const float* bb = beta + b * NBETA;
#pragma unroll
  for (int k = 0; k < NBETA; ++k) acc += bb[k] * SJ[k * 72 + r];
  J[idx] = acc;
}

// Rodrigues per (b): writes Rs[b][24][9] and transposed pose_feature pfT[207][512]
__global__ void k_rod(const float* __restrict__ theta, float* __restrict__ Rs,
                      float* __restrict__ pfT) {
  int b = blockIdx.x * 64 + threadIdx.x;
  if (b >= NBATCH) return;
  for (int j = 0; j < NJNT; ++j) {
    float a0 = theta[b * 72 + j * 3 + 0];
    float a1 = theta[b * 72 + j * 3 + 1];
    float a2 = theta[b * 72 + j * 3 + 2];
    float e0 = a0 + 1e-8f, e1 = a1 + 1e-8f, e2 = a2 + 1e-8f;
    float ang = sqrtf(e0 * e0 + e1 * e1 + e2 * e2);
    float inv = 1.0f / ang;
    float h = 0.5f * ang;
    float w = cosf(h), s = sinf(h);
    float x = a0 * inv * s, y = a1 * inv * s, z = a2 * inv * s;
    float R[9];
    R[0] = w*w + x*x - y*y - z*z; R[1] = 2.f*(x*y - w*z); R[2] = 2.f*(x*z + w*y);
    R[3] = 2.f*(x*y + w*z); R[4] = w*w - x*x + y*y - z*z; R[5] = 2.f*(y*z - w*x);
    R[6] = 2.f*(x*z - w*y); R[7] = 2.f*(y*z + w*x); R[8] = w*w - x*x - y*y + z*z;
#pragma unroll
    for (int r = 0; r < 9; ++r) Rs[b * 216 + j * 9 + r] = R[r];
    if (j >= 1) {
#pragma unroll
      for (int r = 0; r < 9; ++r) {
        float pv = R[r] - ((r % 4 == 0) ? 1.0f : 0.0f);  // subtract eye(3)
        pfT[((j - 1) * 9 + r) * NBATCH + b] = pv;
      }
    }
  }
}

// Kinematic chain per batch: A[b][24][12] (rows 0..2 of the relative 4x4s)
__global__ void k_chain(const float* __restrict__ Rs, const float* __restrict__ Jin,
                        float* __restrict__ A) {
  int b = blockIdx.x * 64 + threadIdx.x;
  if (b >= NBATCH) return;
  const float* Jb = Jin + b * 72;
  const float* Rb = Rs + b * 216;
  float* Ab = A + b * 288;
#pragma unroll
  for (int r = 0; r < 3; ++r) {
#pragma unroll
    for (int c = 0; c < 3; ++c) Ab[r * 4 + c] = Rb[r * 3 + c];
    Ab[r * 4 + 3] = Jb[r];
  }
  for (int i = 1; i < NJNT; ++i) {
    int p = d_par[i];
    const float* P = Ab + p * 12;
    const float* R = Rb + i * 9;
    float t0 = Jb[i * 3 + 0] - Jb[p * 3 + 0];
    float t1 = Jb[i * 3 + 1] - Jb[p * 3 + 1];
    float t2 = Jb[i * 3 + 2] - Jb[p * 3 + 2];
    float* O = Ab + i * 12;
#pragma unroll
    for (int r = 0; r < 3; ++r) {
      float p0 = P[r * 4 + 0], p1 = P[r * 4 + 1], p2 = P[r * 4 + 2], p3 = P[r * 4 + 3];
#pragma unroll
      for (int c = 0; c < 3; ++c)
        O[r * 4 + c] = p0 * R[0 + c] + p1 * R[3 + c] + p2 * R[6 + c];
      O[r * 4 + 3] = p0 * t0 + p1 * t1 + p2 * t2 + p3;
    }
  }
  for (int i = 0; i < NJNT; ++i) {
    float jx = Jb[i * 3 + 0], jy = Jb[i * 3 + 1], jz = Jb[i * 3 + 2];
    float* O = Ab + i * 12;
#pragma unroll
    for (int r = 0; r < 3; ++r)
      O[r * 4 + 3] -= O[r * 4 + 0] * jx + O[r * 4 + 1] * jy + O[r * 4 + 2] * jz;
  }
}

// vp[b,n] = vtmpl[n] + sum_k betaT[k,b]*sdirs[k,n] + sum_k pfT[k,b]*pdirs[k,n]
// Each thread: 1 column n, BT batches. pfT/betaT reads are wave-uniform -> s_load.
__global__ void __launch_bounds__(256) k_vposed(const float* __restrict__ pfT,
                                                const float* __restrict__ pdirs,
                                                const float* __restrict__ betaT,
                                                const float* __restrict__ sdirs,
                                                const float* __restrict__ vtmpl,
                                                float* __restrict__ vp) {
  int n = blockIdx.x * 256 + threadIdx.x;
  if (n >= N3) return;
  int b0 = blockIdx.y * BT;
  float acc[BT];
  float vt = vtmpl[n];
#pragma unroll
  for (int i = 0; i < BT; ++i) acc[i] = vt;
#pragma unroll
  for (int k = 0; k < NBETA; ++k) {
    float sd = sdirs[(size_t)k * N3 + n];
    const float* bt = betaT + k * NBATCH + b0;  // uniform across lanes
#pragma unroll
    for (int i = 0; i < BT; ++i) acc[i] += bt[i] * sd;
  }
#pragma unroll 2
  for (int k = 0; k < NPF; ++k) {
    float pd = pdirs[(size_t)k * N3 + n];
    const float* pfk = pfT + k * NBATCH + b0;   // uniform across lanes
#pragma unroll
    for (int i = 0; i < BT; ++i) acc[i] += pfk[i] * pd;
  }
#pragma unroll
  for (int i = 0; i < BT; ++i)
    vp[(size_t)(b0 + i) * N3 + n] = acc[i];
}

// Fused LBS + vertex transform + joint regression; grid (512 batches, VS vertex chunks)
__global__ void __launch_bounds__(256) k_lbs(const float* __restrict__ vp,
                                             const float* __restrict__ lbsT,
                                             const float* __restrict__ jrT,
                                             const float* __restrict__ A,
                                             float* __restrict__ out) {
  int b = blockIdx.x, tid = threadIdx.x;
  int v0 = blockIdx.y * VCHUNK;
  int vend = v0 + VCHUNK;
  const float* Ab = A + b * 288;
  float acc[NJO * 3];
#pragma unroll
  for (int i = 0; i < NJO * 3; ++i) acc[i] = 0.f;
  for (int v = v0 + tid; v < vend; v += 256) {
    float x = vp[(size_t)b * N3 + v * 3 + 0];
    float y = vp[(size_t)b * N3 + v * 3 + 1];
    float z = vp[(size_t)b * N3 + v * 3 + 2];
    // T-form: T = sum_k w_k * A_k (3x4), then apply once.
    float t[12];
    {
      float w = lbsT[v];
      float4 A0 = *(const float4*)(Ab + 0);
      float4 A1 = *(const float4*)(Ab + 4);
      float4 A2 = *(const float4*)(Ab + 8);
      t[0] = w*A0.x; t[1] = w*A0.y; t[2]  = w*A0.z; t[3]  = w*A0.w;
      t[4] = w*A1.x; t[5] = w*A1.y; t[6]  = w*A1.z; t[7]  = w*A1.w;
      t[8] = w*A2.x; t[9] = w*A2.y; t[10] = w*A2.z; t[11] = w*A2.w;
    }
#pragma unroll
    for (int k = 1; k < NJNT; ++k) {
      float w = lbsT[k * NV + v];
      float4 A0 = *(const float4*)(Ab + k * 12 + 0);  // uniform -> s_load
      float4 A1 = *(const float4*)(Ab + k * 12 + 4);
      float4 A2 = *(const float4*)(Ab + k * 12 + 8);
      t[0] += w*A0.x; t[1] += w*A0.y; t[2]  += w*A0.z; t[3]  += w*A0.w;
      t[4] += w*A1.x; t[5] += w*A1.y; t[6]  += w*A1.z; t[7]  += w*A1.w;
      t[8] += w*A2.x; t[9] += w*A2.y; t[10] += w*A2.z; t[11] += w*A2.w;
    }
    float vx = t[0]*x + t[1]*y + t[2]*z  + t[3];
    float vy = t[4]*x + t[5]*y + t[6]*z  + t[7];
    float vz = t[8]*x + t[9]*y + t[10]*z + t[11];
#pragma unroll
    for (int j = 0; j < NJO; ++j) {
      float w = jrT[j * NV + v];
      acc[j * 3 + 0] += w * vx;
      acc[j * 3 + 1] += w * vy;
      acc[j * 3 + 2] += w * vz;
    }
  }
  __shared__ float red[4][NJO * 3];
  int lane = tid & 63, wid = tid >> 6;
#pragma unroll
  for (int i = 0; i < NJO * 3; ++i) {
    float v = acc[i];
    v += __shfl_xor(v, 1);  v += __shfl_xor(v, 2);  v += __shfl_xor(v, 4);
    v += __shfl_xor(v, 8);  v += __shfl_xor(v, 16); v += __shfl_xor(v, 32);
    if (lane == 0) red[wid][i] = v;
  }
  __syncthreads();
  if (tid < NJO * 3)
    atomicAdd(out + b * NJO * 3 + tid,
              red[0][tid] + red[1][tid] + red[2][tid] + red[3][tid]);
}

extern "C" void kernel_launch(void* const* d_in, const int* in_sizes, int n_in,
                              void* d_out, int out_size, void* d_ws, size_t ws_size,
                              hipStream_t stream) {
  const float* beta  = (const float*)d_in[0];
  const float* theta = (const float*)d_in[1];
  const float* vtmpl = (const float*)d_in[2];
  const float* sdirs = (const float*)d_in[3];
  const float* Jreg  = (const float*)d_in[4];
  const float* pdirs = (const float*)d_in[5];
  const float* lbs   = (const float*)d_in[6];
  const float* jreg2 = (const float*)d_in[7];
  float* out = (float*)d_out;

  float* ws    = (float*)d_ws;
  float* vp    = ws;                                  // 512*20670
  float* Rs    = vp    + (size_t)NBATCH * N3;         // 512*216
  float* pfT   = Rs    + (size_t)NBATCH * 216;        // 207*512
  float* Jout  = pfT   + (size_t)NPF * NBATCH;        // 512*72
  float* A     = Jout  + (size_t)NBATCH * 72;         // 512*288
  float* lbsT  = A     + (size_t)NBATCH * 288;        // 24*6890
  float* jrT   = lbsT  + (size_t)NJNT * NV;           // 19*6890
  float* betaT = jrT   + (size_t)NJO * NV;            // 10*512
  float* SJ    = betaT + (size_t)NBETA * NBATCH;      // 11*72

  hipMemsetAsync(out, 0, (size_t)out_size * sizeof(float), stream);
  k_transpose<<<dim3((NV * NJNT + 255) / 256), 256, 0, stream>>>(lbs, jreg2, beta, lbsT, jrT, betaT);
  k_SJ<<<dim3(NJNT, NBETA + 1), 256, 0, stream>>>(Jreg, sdirs, vtmpl, SJ);
  k_rod<<<dim3(8), 64, 0, stream>>>(theta, Rs, pfT);
  k_Jsmall<<<dim3((NBATCH * 72 + 255) / 256), 256, 0, stream>>>(beta, SJ, Jout);
  k_chain<<<dim3(8), 64, 0, stream>>>(Rs, Jout, A);
  k_vposed<<<dim3((N3 + 255) / 256, NBATCH / BT), 256, 0, stream>>>(pfT, pdirs, betaT, sdirs, vtmpl, vp);
  k_lbs<<<dim3(NBATCH, VS), 256, 0, stream>>>(vp, lbsT, jrT, A, out);
}

// Round 3
// 269.395 us; speedup vs baseline: 1.1499x; 1.0060x over previous
//
#include <hip/hip_runtime.h>
#include <math.h>

#define NV 6890
#define N3 20670      // NV*3
#define NJNT 24
#define NBETA 10
#define NPF 207
#define NJO 19
#define NBATCH 512
#define BT 32         // batch tile for posedirs GEMM
#define SKV 4         // vertex chunks in k_skin / k_joints
#define SKCH 1723     // ceil(NV/SKV)
#define SKIT 27       // ceil(SKCH/64)

__constant__ int d_par[NJNT] = {0,0,0,0,1,2,3,4,5,6,7,8,9,9,9,12,13,14,16,17,18,19,20,21};

// Pack weights for coalesced access:
//  lbsP[w][v][8]: floats w[v, 6w..6w+6) + 2 pad  (wave-split layout)
//  jrP[q][v]: float4 = jr[v, 4q..4q+4) (pad j>=19 with 0)
//  betaT[k][b]
__global__ void k_pack(const float* __restrict__ lbs, const float* __restrict__ jr,
                       const float* __restrict__ beta,
                       float* __restrict__ lbsP, float4* __restrict__ jrP,
                       float* __restrict__ betaT) {
  int v = blockIdx.x * 256 + threadIdx.x;
  if (v < NV) {
#pragma unroll
    for (int w = 0; w < 4; ++w) {
      float* o = lbsP + ((size_t)w * NV + v) * 8;
#pragma unroll
      for (int i = 0; i < 6; ++i) o[i] = lbs[v * NJNT + w * 6 + i];
      o[6] = 0.f; o[7] = 0.f;
    }
#pragma unroll
    for (int q = 0; q < 5; ++q) {
      float4 t;
      t.x = jr[v * NJO + 4 * q + 0];
      t.y = jr[v * NJO + 4 * q + 1];
      t.z = jr[v * NJO + 4 * q + 2];
      t.w = (4 * q + 3 < NJO) ? jr[v * NJO + 4 * q + 3] : 0.f;
      jrP[(size_t)q * NV + v] = t;
    }
  }
  int idx = blockIdx.x * 256 + threadIdx.x;
  if (idx < NBATCH * NBETA) {
    int k = idx / NBATCH, b = idx - k * NBATCH;
    betaT[idx] = beta[b * NBETA + k];
  }
}

// SJ[k][j][c] = sum_v Jreg[v,j] * sdirs[k,(v,c)]  for k<10; k==10 row uses v_template
__global__ void __launch_bounds__(256) k_SJ(const float* __restrict__ Jreg,
                                            const float* __restrict__ sdirs,
                                            const float* __restrict__ vtmpl,
                                            float* __restrict__ SJ) {
  int j = blockIdx.x;   // 0..23
  int k = blockIdx.y;   // 0..10
  int tid = threadIdx.x;
  const float* src = (k < NBETA) ? (sdirs + (size_t)k * N3) : vtmpl;
  float a0 = 0.f, a1 = 0.f, a2 = 0.f;
  for (int v = tid; v < NV; v += 256) {
    float w = Jreg[v * NJNT + j];
    a0 += w * src[v * 3 + 0];
    a1 += w * src[v * 3 + 1];
    a2 += w * src[v * 3 + 2];
  }
  __shared__ float red[4][3];
  int lane = tid & 63, wid = tid >> 6;
#pragma unroll
  for (int s = 1; s < 64; s <<= 1) {
    a0 += __shfl_xor(a0, s); a1 += __shfl_xor(a1, s); a2 += __shfl_xor(a2, s);
  }
  if (lane == 0) { red[wid][0] = a0; red[wid][1] = a1; red[wid][2] = a2; }
  __syncthreads();
  if (tid == 0) {
    float* o = SJ + (k * NJNT + j) * 3;
    o[0] = red[0][0] + red[1][0] + red[2][0] + red[3][0];
    o[1] = red[0][1] + red[1][1] + red[2][1] + red[3][1];
    o[2] = red[0][2] + red[1][2] + red[2][2] + red[3][2];
  }
}

// J[b][j][c] = SJ[10][j][c] + sum_k beta[b,k]*SJ[k][j][c]
__global__ void k_Jsmall(const float* __restrict__ beta, const float* __restrict__ SJ,
                         float* __restrict__ J) {
  int idx = blockIdx.x * 256 + threadIdx.x;
  if (idx >= NBATCH * 72) return;
  int b = idx / 72, r = idx - b * 72;
  float acc = SJ[NBETA * 72 + r];
  const float* bb = beta + b * NBETA;
#pragma unroll
  for (int k = 0; k < NBETA; ++k) acc += bb[k] * SJ[k * 72 + r];
  J[idx] = acc;
}

// Rodrigues per (b): writes Rs[b][24][9] and transposed pose_feature pfT[207][512]
__global__ void k_rod(const float* __restrict__ theta, float* __restrict__ Rs,
                      float* __restrict__ pfT) {
  int b = blockIdx.x * 64 + threadIdx.x;
  if (b >= NBATCH) return;
  for (int j = 0; j < NJNT; ++j) {
    float a0 = theta[b * 72 + j * 3 + 0];
    float a1 = theta[b * 72 + j * 3 + 1];
    float a2 = theta[b * 72 + j * 3 + 2];
    float e0 = a0 + 1e-8f, e1 = a1 + 1e-8f, e2 = a2 + 1e-8f;
    float ang = sqrtf(e0 * e0 + e1 * e1 + e2 * e2);
    float inv = 1.0f / ang;
    float h = 0.5f * ang;
    float w = cosf(h), s = sinf(h);
    float x = a0 * inv * s, y = a1 * inv * s, z = a2 * inv * s;
    float R[9];
    R[0] = w*w + x*x - y*y - z*z; R[1] = 2.f*(x*y - w*z); R[2] = 2.f*(x*z + w*y);
    R[3] = 2.f*(x*y + w*z); R[4] = w*w - x*x + y*y - z*z; R[5] = 2.f*(y*z - w*x);
    R[6] = 2.f*(x*z - w*y); R[7] = 2.f*(y*z + w*x); R[8] = w*w - x*x - y*y + z*z;
#pragma unroll
    for (int r = 0; r < 9; ++r) Rs[b * 216 + j * 9 + r] = R[r];
    if (j >= 1) {
#pragma unroll
      for (int r = 0; r < 9; ++r) {
        float pv = R[r] - ((r % 4 == 0) ? 1.0f : 0.0f);  // subtract eye(3)
        pfT[((j - 1) * 9 + r) * NBATCH + b] = pv;
      }
    }
  }
}

// Kinematic chain per batch: A[b][24][12] (rows 0..2 of the relative 4x4s)
__global__ void k_chain(const float* __restrict__ Rs, const float* __restrict__ Jin,
                        float* __restrict__ A) {
  int b = blockIdx.x * 64 + threadIdx.x;
  if (b >= NBATCH) return;
  const float* Jb = Jin + b * 72;
  const float* Rb = Rs + b * 216;
  float* Ab = A + b * 288;
#pragma unroll
  for (int r = 0; r < 3; ++r) {
#pragma unroll
    for (int c = 0; c < 3; ++c) Ab[r * 4 + c] = Rb[r * 3 + c];
    Ab[r * 4 + 3] = Jb[r];
  }
  for (int i = 1; i < NJNT; ++i) {
    int p = d_par[i];
    const float* P = Ab + p * 12;
    const float* R = Rb + i * 9;
    float t0 = Jb[i * 3 + 0] - Jb[p * 3 + 0];
    float t1 = Jb[i * 3 + 1] - Jb[p * 3 + 1];
    float t2 = Jb[i * 3 + 2] - Jb[p * 3 + 2];
    float* O = Ab + i * 12;
#pragma unroll
    for (int r = 0; r < 3; ++r) {
      float p0 = P[r * 4 + 0], p1 = P[r * 4 + 1], p2 = P[r * 4 + 2], p3 = P[r * 4 + 3];
#pragma unroll
      for (int c = 0; c < 3; ++c)
        O[r * 4 + c] = p0 * R[0 + c] + p1 * R[3 + c] + p2 * R[6 + c];
      O[r * 4 + 3] = p0 * t0 + p1 * t1 + p2 * t2 + p3;
    }
  }
  for (int i = 0; i < NJNT; ++i) {
    float jx = Jb[i * 3 + 0], jy = Jb[i * 3 + 1], jz = Jb[i * 3 + 2];
    float* O = Ab + i * 12;
#pragma unroll
    for (int r = 0; r < 3; ++r)
      O[r * 4 + 3] -= O[r * 4 + 0] * jx + O[r * 4 + 1] * jy + O[r * 4 + 2] * jz;
  }
}

// vp[b,n] = vtmpl[n] + sum_k betaT[k,b]*sdirs[k,n] + sum_k pfT[k,b]*pdirs[k,n]
__global__ void __launch_bounds__(256) k_vposed(const float* __restrict__ pfT,
                                                const float* __restrict__ pdirs,
                                                const float* __restrict__ betaT,
                                                const float* __restrict__ sdirs,
                                                const float* __restrict__ vtmpl,
                                                float* __restrict__ vp) {
  int n = blockIdx.x * 256 + threadIdx.x;
  if (n >= N3) return;
  int b0 = blockIdx.y * BT;
  float acc[BT];
  float vt = vtmpl[n];
#pragma unroll
  for (int i = 0; i < BT; ++i) acc[i] = vt;
#pragma unroll
  for (int k = 0; k < NBETA; ++k) {
    float sd = sdirs[(size_t)k * N3 + n];
    const float* bt = betaT + k * NBATCH + b0;  // uniform across lanes
#pragma unroll
    for (int i = 0; i < BT; ++i) acc[i] += bt[i] * sd;
  }
#pragma unroll 2
  for (int k = 0; k < NPF; ++k) {
    float pd = pdirs[(size_t)k * N3 + n];
    const float* pfk = pfT + k * NBATCH + b0;   // uniform across lanes
#pragma unroll
    for (int i = 0; i < BT; ++i) acc[i] += pfk[i] * pd;
  }
#pragma unroll
  for (int i = 0; i < BT; ++i)
    vp[(size_t)(b0 + i) * N3 + n] = acc[i];
}

// Skinning: verts[b,v,:] = (sum_k w[v,k] A[b,k]) . [vp;1]
// Joints split across 4 waves (6 each); A chunk register-resident per wave.
__global__ void __launch_bounds__(256) k_skin(const float* __restrict__ vp,
                                              const float* __restrict__ lbsP,
                                              const float* __restrict__ A,
                                              float* __restrict__ verts) {
  int b = blockIdx.y, tid = threadIdx.x;
  int wid = tid >> 6, lane = tid & 63;
  __shared__ float As[288];
  __shared__ float red[64][13];   // stride 13: 2-way bank alias (free)
  for (int i = tid; i < 288; i += 256) As[i] = A[b * 288 + i];
  __syncthreads();
  float4 a[18];
#pragma unroll
  for (int i = 0; i < 18; ++i) a[i] = *(const float4*)(As + wid * 72 + i * 4);
  int v0 = blockIdx.x * SKCH;
  int vend = v0 + SKCH; if (vend > NV) vend = NV;
  for (int it = 0; it < SKIT; ++it) {
    int v = v0 + it * 64 + lane;
    bool act = (v < vend);
    float vx = 0.f, vy = 0.f, vz = 0.f;
    if (act) {
      float x = vp[(size_t)b * N3 + v * 3 + 0];
      float y = vp[(size_t)b * N3 + v * 3 + 1];
      float z = vp[(size_t)b * N3 + v * 3 + 2];
      const float4* wp = (const float4*)(lbsP + ((size_t)wid * NV + v) * 8);
      float4 w0 = wp[0], w1 = wp[1];
      float wv[6] = {w0.x, w0.y, w0.z, w0.w, w1.x, w1.y};
      float t[12];
#pragma unroll
      for (int i = 0; i < 12; ++i) t[i] = 0.f;
#pragma unroll
      for (int k = 0; k < 6; ++k) {
        float w = wv[k];
        float4 A0 = a[k * 3 + 0], A1 = a[k * 3 + 1], A2 = a[k * 3 + 2];
        t[0] += w * A0.x; t[1] += w * A0.y; t[2]  += w * A0.z; t[3]  += w * A0.w;
        t[4] += w * A1.x; t[5] += w * A1.y; t[6]  += w * A1.z; t[7]  += w * A1.w;
        t[8] += w * A2.x; t[9] += w * A2.y; t[10] += w * A2.z; t[11] += w * A2.w;
      }
      vx = t[0] * x + t[1] * y + t[2]  * z + t[3];
      vy = t[4] * x + t[5] * y + t[6]  * z + t[7];
      vz = t[8] * x + t[9] * y + t[10] * z + t[11];
    }
    red[lane][wid * 3 + 0] = vx;
    red[lane][wid * 3 + 1] = vy;
    red[lane][wid * 3 + 2] = vz;
    __syncthreads();
    if (wid == 0 && act) {
      float sx = red[lane][0] + red[lane][3] + red[lane][6] + red[lane][9];
      float sy = red[lane][1] + red[lane][4] + red[lane][7] + red[lane][10];
      float sz = red[lane][2] + red[lane][5] + red[lane][8] + red[lane][11];
      verts[(size_t)b * N3 + v * 3 + 0] = sx;
      verts[(size_t)b * N3 + v * 3 + 1] = sy;
      verts[(size_t)b * N3 + v * 3 + 2] = sz;
    }
    __syncthreads();
  }
}

// joints[b,j,:] += sum_v jr[v,j] * verts[b,v,:]
__global__ void __launch_bounds__(256) k_joints(const float* __restrict__ verts,
                                                const float4* __restrict__ jrP,
                                                float* __restrict__ out) {
  int b = blockIdx.x, tid = threadIdx.x;
  int v0 = blockIdx.y * SKCH;
  int vend = v0 + SKCH; if (vend > NV) vend = NV;
  float acc[NJO * 3];
#pragma unroll
  for (int i = 0; i < NJO * 3; ++i) acc[i] = 0.f;
  for (int v = v0 + tid; v < vend; v += 256) {
    float x = verts[(size_t)b * N3 + v * 3 + 0];
    float y = verts[(size_t)b * N3 + v * 3 + 1];
    float z = verts[(size_t)b * N3 + v * 3 + 2];
#pragma unroll
    for (int q = 0; q < 5; ++q) {
      float4 w4 = jrP[(size_t)q * NV + v];
      float wv[4] = {w4.x, w4.y, w4.z, w4.w};
#pragma unroll
      for (int m = 0; m < ((q == 4) ? 3 : 4); ++m) {
        int j = q * 4 + m;
        acc[j * 3 + 0] += wv[m] * x;
        acc[j * 3 + 1] += wv[m] * y;
        acc[j * 3 + 2] += wv[m] * z;
      }
    }
  }
  __shared__ float red[4][NJO * 3];
  int lane = tid & 63, wid = tid >> 6;
#pragma unroll
  for (int i = 0; i < NJO * 3; ++i) {
    float v = acc[i];
    v += __shfl_xor(v, 1);  v += __shfl_xor(v, 2);  v += __shfl_xor(v, 4);
    v += __shfl_xor(v, 8);  v += __shfl_xor(v, 16); v += __shfl_xor(v, 32);
    if (lane == 0) red[wid][i] = v;
  }
  __syncthreads();
  if (tid < NJO * 3)
    atomicAdd(out + b * NJO * 3 + tid,
              red[0][tid] + red[1][tid] + red[2][tid] + red[3][tid]);
}

extern "C" void kernel_launch(void* const* d_in, const int* in_sizes, int n_in,
                              void* d_out, int out_size, void* d_ws, size_t ws_size,
                              hipStream_t stream) {
  const float* beta  = (const float*)d_in[0];
  const float* theta = (const float*)d_in[1];
  const float* vtmpl = (const float*)d_in[2];
  const float* sdirs = (const float*)d_in[3];
  const float* Jreg  = (const float*)d_in[4];
  const float* pdirs = (const float*)d_in[5];
  const float* lbs   = (const float*)d_in[6];
  const float* jreg2 = (const float*)d_in[7];
  float* out = (float*)d_out;

  float* ws    = (float*)d_ws;
  float* vp    = ws;                                  // 512*20670
  float* verts = vp    + (size_t)NBATCH * N3;         // 512*20670
  float* Rs    = verts + (size_t)NBATCH * N3;         // 512*216
  float* pfT   = Rs    + (size_t)NBATCH * 216;        // 207*512
  float* Jout  = pfT   + (size_t)NPF * NBATCH;        // 512*72
  float* A     = Jout  + (size_t)NBATCH * 72;         // 512*288
  float* lbsP  = A     + (size_t)NBATCH * 288;        // 4*6890*8
  float* jrP   = lbsP  + (size_t)4 * NV * 8;          // 5*6890*4
  float* betaT = jrP   + (size_t)5 * NV * 4;          // 10*512
  float* SJ    = betaT + (size_t)NBETA * NBATCH;      // 11*72

  hipMemsetAsync(out, 0, (size_t)out_size * sizeof(float), stream);
  k_pack<<<dim3((NV + 255) / 256), 256, 0, stream>>>(lbs, jreg2, beta, lbsP, (float4*)jrP, betaT);
  k_SJ<<<dim3(NJNT, NBETA + 1), 256, 0, stream>>>(Jreg, sdirs, vtmpl, SJ);
  k_rod<<<dim3(8), 64, 0, stream>>>(theta, Rs, pfT);
  k_Jsmall<<<dim3((NBATCH * 72 + 255) / 256), 256, 0, stream>>>(beta, SJ, Jout);
  k_chain<<<dim3(8), 64, 0, stream>>>(Rs, Jout, A);
  k_vposed<<<dim3((N3 + 255) / 256, NBATCH / BT), 256, 0, stream>>>(pfT, pdirs, betaT, sdirs, vtmpl, vp);
  k_skin<<<dim3(SKV, NBATCH), 256, 0, stream>>>(vp, lbsP, A, verts);
  k_joints<<<dim3(NBATCH, SKV), 256, 0, stream>>>(verts, (const float4*)jrP, out);
}

// Round 4
// 222.771 us; speedup vs baseline: 1.3906x; 1.2093x over previous
//
#include <hip/hip_runtime.h>
#include <math.h>

#define NV 6890
#define N3 20670       // NV*3
#define NJNT 24
#define NBETA 10
#define NPF 207
#define NJO 19
#define NBATCH 512
#define NJK 456        // NJO*NJNT
#define NJKP 512       // padded jk (GEMM N)
#define NCOEF 218      // [pf 207 | beta 10 | 1]
#define PROWS 655      // 218*3 + c0 row
#define PROWSP 704     // padded (GEMM M)
#define KPAD 6912      // 8 * 864
#define KSPLIT 8
#define KCH 864        // 27 * 32
#define CSTR 224       // pfc row stride
#define BCH 4          // batches per k_S block

__constant__ int d_par[NJNT] = {0,0,0,0,1,2,3,4,5,6,7,8,9,9,9,12,13,14,16,17,18,19,20,21};

// ---- transpose jr (V,19)->(19,V) and w (V,24)->(24,V) ----
__global__ void k_tr(const float* __restrict__ jr, const float* __restrict__ lbs,
                     float* __restrict__ jrT, float* __restrict__ wT) {
  int idx = blockIdx.x * 256 + threadIdx.x;
  if (idx < NV * NJO)  { int v = idx / NJO,  j = idx - v * NJO;  jrT[j * NV + v] = jr[idx]; }
  if (idx < NV * NJNT) { int v = idx / NJNT, k = idx - v * NJNT; wT[k * NV + v]  = lbs[idx]; }
}

// ---- Cm[jk][KPAD]: jr[v,j]*w[v,k]; zero pads ----
__global__ void __launch_bounds__(256) k_Cm(const float* __restrict__ jrT,
                                            const float* __restrict__ wT,
                                            float* __restrict__ Cm) {
  int v = blockIdx.x * 256 + threadIdx.x;   // 27*256 = 6912
  int j = blockIdx.y;                        // 0..18
  float jw = (v < NV) ? jrT[j * NV + v] : 0.f;
#pragma unroll
  for (int k = 0; k < NJNT; ++k) {
    float wv = (v < NV) ? wT[k * NV + v] : 0.f;
    Cm[(size_t)(j * NJNT + k) * KPAD + v] = jw * wv;
  }
}

// zero the pad rows of Cm (jk in [456,512))
__global__ void k_Czero(float* __restrict__ Cm) {
  int v = blockIdx.x * 256 + threadIdx.x;
  int row = NJK + blockIdx.y;
  Cm[(size_t)row * KPAD + v] = 0.f;
}

// ---- Pm[row][KPAD]: rows 0..620 pdirs, 621..650 sdirs, 651..653 vtmpl, 654 ones, rest 0
__global__ void __launch_bounds__(256) k_Pm(const float* __restrict__ pdirs,
                                            const float* __restrict__ sdirs,
                                            const float* __restrict__ vtmpl,
                                            float* __restrict__ Pm) {
  int v = blockIdx.y * 256 + threadIdx.x;
  int r = blockIdx.x;                        // 0..703
  float val = 0.f;
  if (v < NV) {
    if (r < 621) {
      int m = r / 3, q = r - m * 3;
      val = pdirs[(size_t)m * N3 + v * 3 + q];
    } else if (r < 651) {
      int rr = r - 621; int m = rr / 3, q = rr - m * 3;
      val = sdirs[(size_t)m * N3 + v * 3 + q];
    } else if (r < 654) {
      val = vtmpl[v * 3 + (r - 651)];
    } else if (r == 654) {
      val = 1.0f;
    }
  }
  Pm[(size_t)r * KPAD + v] = val;
}

// ---- GEMM: Dpart[z][m][n] = sum_{k in chunk z} Pm[m][k] * Cm[n][k] ----
__global__ void __launch_bounds__(256) k_gemm(const float* __restrict__ Pm,
                                              const float* __restrict__ Cm,
                                              float* __restrict__ Dpart) {
  int m0 = blockIdx.x * 64;   // 11
  int n0 = blockIdx.y * 64;   // 8
  int kb0 = blockIdx.z * KCH; // 8
  __shared__ float Ps[32][68];
  __shared__ float Cs[32][68];
  int t = threadIdx.x;
  int lk = t & 31, lr = t >> 5;       // stage indices
  int tx = t & 15, ty = t >> 4;       // compute indices
  float acc[4][4];
#pragma unroll
  for (int i = 0; i < 4; ++i)
#pragma unroll
    for (int j = 0; j < 4; ++j) acc[i][j] = 0.f;

  for (int kk = 0; kk < KCH / 32; ++kk) {
    int kb = kb0 + kk * 32;
#pragma unroll
    for (int i = 0; i < 8; ++i) {
      int row = lr + 8 * i;
      Ps[lk][row] = Pm[(size_t)(m0 + row) * KPAD + kb + lk];
      Cs[lk][row] = Cm[(size_t)(n0 + row) * KPAD + kb + lk];
    }
    __syncthreads();
#pragma unroll
    for (int k = 0; k < 32; ++k) {
      float4 a = *(const float4*)&Ps[k][ty * 4];
      float4 b = *(const float4*)&Cs[k][tx * 4];
      float av[4] = {a.x, a.y, a.z, a.w};
      float bv[4] = {b.x, b.y, b.z, b.w};
#pragma unroll
      for (int i = 0; i < 4; ++i)
#pragma unroll
        for (int j = 0; j < 4; ++j) acc[i][j] += av[i] * bv[j];
    }
    __syncthreads();
  }
  float* dst = Dpart + ((size_t)blockIdx.z * PROWSP + m0) * NJKP + n0;
#pragma unroll
  for (int i = 0; i < 4; ++i) {
    float4 o = make_float4(acc[i][0], acc[i][1], acc[i][2], acc[i][3]);
    *(float4*)(dst + (size_t)(ty * 4 + i) * NJKP + tx * 4) = o;
  }
}

// ---- reduce K-split partials ----
__global__ void k_redD(const float* __restrict__ Dpart, float* __restrict__ D) {
  int i = blockIdx.x * 256 + threadIdx.x;
  if (i >= PROWSP * NJKP) return;
  float s = 0.f;
#pragma unroll
  for (int z = 0; z < KSPLIT; ++z) s += Dpart[(size_t)z * PROWSP * NJKP + i];
  D[i] = s;
}

// ---- SJ[k][j][c] for J reassociation (k==10 row = v_template) ----
__global__ void __launch_bounds__(256) k_SJ(const float* __restrict__ Jreg,
                                            const float* __restrict__ sdirs,
                                            const float* __restrict__ vtmpl,
                                            float* __restrict__ SJ) {
  int j = blockIdx.x, k = blockIdx.y, tid = threadIdx.x;
  const float* src = (k < NBETA) ? (sdirs + (size_t)k * N3) : vtmpl;
  float a0 = 0.f, a1 = 0.f, a2 = 0.f;
  for (int v = tid; v < NV; v += 256) {
    float w = Jreg[v * NJNT + j];
    a0 += w * src[v * 3 + 0];
    a1 += w * src[v * 3 + 1];
    a2 += w * src[v * 3 + 2];
  }
  __shared__ float red[4][3];
  int lane = tid & 63, wid = tid >> 6;
#pragma unroll
  for (int s = 1; s < 64; s <<= 1) {
    a0 += __shfl_xor(a0, s); a1 += __shfl_xor(a1, s); a2 += __shfl_xor(a2, s);
  }
  if (lane == 0) { red[wid][0] = a0; red[wid][1] = a1; red[wid][2] = a2; }
  __syncthreads();
  if (tid == 0) {
    float* o = SJ + (k * NJNT + j) * 3;
    o[0] = red[0][0] + red[1][0] + red[2][0] + red[3][0];
    o[1] = red[0][1] + red[1][1] + red[2][1] + red[3][1];
    o[2] = red[0][2] + red[1][2] + red[2][2] + red[3][2];
  }
}

__global__ void k_Jsmall(const float* __restrict__ beta, const float* __restrict__ SJ,
                         float* __restrict__ J) {
  int idx = blockIdx.x * 256 + threadIdx.x;
  if (idx >= NBATCH * 72) return;
  int b = idx / 72, r = idx - b * 72;
  float acc = SJ[NBETA * 72 + r];
  const float* bb = beta + b * NBETA;
#pragma unroll
  for (int k = 0; k < NBETA; ++k) acc += bb[k] * SJ[k * 72 + r];
  J[idx] = acc;
}

// ---- Rodrigues: Rs[b][24][9] and pfc[b][224] = [pf 207 | beta 10 | 1 | pad] ----
__global__ void k_rod(const float* __restrict__ theta, const float* __restrict__ beta,
                      float* __restrict__ Rs, float* __restrict__ pfc) {
  int b = blockIdx.x * 64 + threadIdx.x;
  if (b >= NBATCH) return;
  for (int j = 0; j < NJNT; ++j) {
    float a0 = theta[b * 72 + j * 3 + 0];
    float a1 = theta[b * 72 + j * 3 + 1];
    float a2 = theta[b * 72 + j * 3 + 2];
    float e0 = a0 + 1e-8f, e1 = a1 + 1e-8f, e2 = a2 + 1e-8f;
    float ang = sqrtf(e0 * e0 + e1 * e1 + e2 * e2);
    float inv = 1.0f / ang;
    float h = 0.5f * ang;
    float w = cosf(h), s = sinf(h);
    float x = a0 * inv * s, y = a1 * inv * s, z = a2 * inv * s;
    float R[9];
    R[0] = w*w + x*x - y*y - z*z; R[1] = 2.f*(x*y - w*z); R[2] = 2.f*(x*z + w*y);
    R[3] = 2.f*(x*y + w*z); R[4] = w*w - x*x + y*y - z*z; R[5] = 2.f*(y*z - w*x);
    R[6] = 2.f*(x*z - w*y); R[7] = 2.f*(y*z + w*x); R[8] = w*w - x*x - y*y + z*z;
#pragma unroll
    for (int r = 0; r < 9; ++r) Rs[b * 216 + j * 9 + r] = R[r];
    if (j >= 1) {
#pragma unroll
      for (int r = 0; r < 9; ++r)
        pfc[b * CSTR + (j - 1) * 9 + r] = R[r] - ((r % 4 == 0) ? 1.0f : 0.0f);
    }
  }
#pragma unroll
  for (int i = 0; i < NBETA; ++i) pfc[b * CSTR + NPF + i] = beta[b * NBETA + i];
  pfc[b * CSTR + NPF + NBETA] = 1.0f;
}

// ---- kinematic chain: A[b][24][12] ----
__global__ void k_chain(const float* __restrict__ Rs, const float* __restrict__ Jin,
                        float* __restrict__ A) {
  int b = blockIdx.x * 64 + threadIdx.x;
  if (b >= NBATCH) return;
  const float* Jb = Jin + b * 72;
  const float* Rb = Rs + b * 216;
  float* Ab = A + b * 288;
#pragma unroll
  for (int r = 0; r < 3; ++r) {
#pragma unroll
    for (int c = 0; c < 3; ++c) Ab[r * 4 + c] = Rb[r * 3 + c];
    Ab[r * 4 + 3] = Jb[r];
  }
  for (int i = 1; i < NJNT; ++i) {
    int p = d_par[i];
    const float* P = Ab + p * 12;
    const float* R = Rb + i * 9;
    float t0 = Jb[i * 3 + 0] - Jb[p * 3 + 0];
    float t1 = Jb[i * 3 + 1] - Jb[p * 3 + 1];
    float t2 = Jb[i * 3 + 2] - Jb[p * 3 + 2];
    float* O = Ab + i * 12;
#pragma unroll
    for (int r = 0; r < 3; ++r) {
      float p0 = P[r * 4 + 0], p1 = P[r * 4 + 1], p2 = P[r * 4 + 2], p3 = P[r * 4 + 3];
#pragma unroll
      for (int c = 0; c < 3; ++c)
        O[r * 4 + c] = p0 * R[0 + c] + p1 * R[3 + c] + p2 * R[6 + c];
      O[r * 4 + 3] = p0 * t0 + p1 * t1 + p2 * t2 + p3;
    }
  }
  for (int i = 0; i < NJNT; ++i) {
    float jx = Jb[i * 3 + 0], jy = Jb[i * 3 + 1], jz = Jb[i * 3 + 2];
    float* O = Ab + i * 12;
#pragma unroll
    for (int r = 0; r < 3; ++r)
      O[r * 4 + 3] -= O[r * 4 + 0] * jx + O[r * 4 + 1] * jy + O[r * 4 + 2] * jz;
  }
}

// ---- S[b][jk][q] = sum_r coef[b][r] * D[3r+q][jk]; 4 batches per block ----
__global__ void __launch_bounds__(512) k_S(const float* __restrict__ D,
                                           const float* __restrict__ pfc,
                                           float* __restrict__ S) {
  int jk = threadIdx.x;
  int b0 = blockIdx.x * BCH;
  if (jk >= NJK) return;
  float acc[BCH][3];
#pragma unroll
  for (int i = 0; i < BCH; ++i)
#pragma unroll
    for (int q = 0; q < 3; ++q) acc[i][q] = 0.f;
#pragma unroll 2
  for (int r = 0; r < NCOEF; ++r) {
    float d0 = D[(size_t)(3 * r + 0) * NJKP + jk];
    float d1 = D[(size_t)(3 * r + 1) * NJKP + jk];
    float d2 = D[(size_t)(3 * r + 2) * NJKP + jk];
#pragma unroll
    for (int i = 0; i < BCH; ++i) {
      float c = pfc[(b0 + i) * CSTR + r];  // uniform -> s_load
      acc[i][0] += c * d0;
      acc[i][1] += c * d1;
      acc[i][2] += c * d2;
    }
  }
#pragma unroll
  for (int i = 0; i < BCH; ++i) {
    float* o = S + ((size_t)(b0 + i) * NJK + jk) * 3;
    o[0] = acc[i][0]; o[1] = acc[i][1]; o[2] = acc[i][2];
  }
}

// ---- joints[b,j,c] = sum_k A[b,k,c,:] . [S[b,jk,0..2], c0[jk]] ----
__global__ void k_final(const float* __restrict__ S, const float* __restrict__ D,
                        const float* __restrict__ A, float* __restrict__ out) {
  int idx = blockIdx.x * 256 + threadIdx.x;
  if (idx >= NBATCH * NJO * 3) return;
  int b = idx / 57, r = idx - b * 57;
  int j = r / 3, c = r - j * 3;
  const float* c0 = D + (size_t)654 * NJKP + j * NJNT;
  float acc = 0.f;
#pragma unroll
  for (int k = 0; k < NJNT; ++k) {
    const float* Ar = A + b * 288 + k * 12 + c * 4;
    const float* Sr = S + ((size_t)b * NJK + j * NJNT + k) * 3;
    acc += Ar[0] * Sr[0] + Ar[1] * Sr[1] + Ar[2] * Sr[2] + Ar[3] * c0[k];
  }
  out[idx] = acc;
}

extern "C" void kernel_launch(void* const* d_in, const int* in_sizes, int n_in,
                              void* d_out, int out_size, void* d_ws, size_t ws_size,
                              hipStream_t stream) {
  const float* beta  = (const float*)d_in[0];
  const float* theta = (const float*)d_in[1];
  const float* vtmpl = (const float*)d_in[2];
  const float* sdirs = (const float*)d_in[3];
  const float* Jreg  = (const float*)d_in[4];
  const float* pdirs = (const float*)d_in[5];
  const float* lbs   = (const float*)d_in[6];
  const float* jreg2 = (const float*)d_in[7];
  float* out = (float*)d_out;

  float* ws    = (float*)d_ws;
  float* Cm    = ws;                                     // 512*6912      = 3.54M
  float* Pm    = Cm    + (size_t)NJKP * KPAD;            // 704*6912      = 4.87M
  float* Dpart = Pm    + (size_t)PROWSP * KPAD;          // 8*704*512     = 2.88M
  float* D     = Dpart + (size_t)KSPLIT * PROWSP * NJKP; // 704*512       = 0.36M
  float* S     = D     + (size_t)PROWSP * NJKP;          // 512*456*3     = 0.70M
  float* pfc   = S     + (size_t)NBATCH * NJK * 3;       // 512*224
  float* Rs    = pfc   + (size_t)NBATCH * CSTR;          // 512*216
  float* Jout  = Rs    + (size_t)NBATCH * 216;           // 512*72
  float* A     = Jout  + (size_t)NBATCH * 72;            // 512*288
  float* jrT   = A     + (size_t)NBATCH * 288;           // 19*6890
  float* wT    = jrT   + (size_t)NJO * NV;               // 24*6890
  float* SJ    = wT    + (size_t)NJNT * NV;              // 11*72

  k_tr<<<dim3((NV * NJNT + 255) / 256), 256, 0, stream>>>(jreg2, lbs, jrT, wT);
  k_rod<<<dim3(8), 64, 0, stream>>>(theta, beta, Rs, pfc);
  k_SJ<<<dim3(NJNT, NBETA + 1), 256, 0, stream>>>(Jreg, sdirs, vtmpl, SJ);
  k_Jsmall<<<dim3((NBATCH * 72 + 255) / 256), 256, 0, stream>>>(beta, SJ, Jout);
  k_chain<<<dim3(8), 64, 0, stream>>>(Rs, Jout, A);
  k_Cm<<<dim3(KPAD / 256, NJO), 256, 0, stream>>>(jrT, wT, Cm);
  k_Czero<<<dim3(KPAD / 256, NJKP - NJK), 256, 0, stream>>>(Cm);
  k_Pm<<<dim3(PROWSP, KPAD / 256), 256, 0, stream>>>(pdirs, sdirs, vtmpl, Pm);
  k_gemm<<<dim3(PROWSP / 64, NJKP / 64, KSPLIT), 256, 0, stream>>>(Pm, Cm, Dpart);
  k_redD<<<dim3((PROWSP * NJKP + 255) / 256), 256, 0, stream>>>(Dpart, D);
  k_S<<<dim3(NBATCH / BCH), 512, 0, stream>>>(D, pfc, S);
  k_final<<<dim3((NBATCH * NJO * 3 + 255) / 256), 256, 0, stream>>>(S, D, A, out);
}

// Round 5
// 157.071 us; speedup vs baseline: 1.9722x; 1.4183x over previous
//
#include <hip/hip_runtime.h>
#include <math.h>

#define NV 6890
#define N3 20670       // NV*3
#define NJNT 24
#define NBETA 10
#define NPF 207
#define NJO 19
#define NBATCH 512
#define NJK 456        // NJO*NJNT
#define NJKP 512       // padded jk (GEMM N)
#define NCOEF 218      // [pf 207 | beta 10 | 1]
#define PROWS 655      // 218*3 + c0 row
#define PROWSP 704     // padded (GEMM M)
#define KPAD 6912      // 12 * 576
#define KSPLIT 12
#define KCH 576        // 9 * 64
#define CSTR 224       // pfc row stride
#define BCH 2          // batches per k_S block

typedef __attribute__((ext_vector_type(8))) short bfx8;
typedef __attribute__((ext_vector_type(4))) float fx4;

__constant__ int d_par[NJNT] = {0,0,0,0,1,2,3,4,5,6,7,8,9,9,9,12,13,14,16,17,18,19,20,21};

__device__ inline short f2bf(float f) {
  union { float f; unsigned u; } x; x.f = f;
  unsigned r = (x.u + 0x7fffu + ((x.u >> 16) & 1u)) >> 16;
  return (short)r;
}

// ---- transpose jr (V,19)->(19,V) and w (V,24)->(24,V) ----
__global__ void k_tr(const float* __restrict__ jr, const float* __restrict__ lbs,
                     float* __restrict__ jrT, float* __restrict__ wT) {
  int idx = blockIdx.x * 256 + threadIdx.x;
  if (idx < NV * NJO)  { int v = idx / NJO,  j = idx - v * NJO;  jrT[j * NV + v] = jr[idx]; }
  if (idx < NV * NJNT) { int v = idx / NJNT, k = idx - v * NJNT; wT[k * NV + v]  = lbs[idx]; }
}

// ---- Cb[jk][KPAD] bf16: jr[v,j]*w[v,k]; pads zero ----
__global__ void __launch_bounds__(256) k_Cm(const float* __restrict__ jrT,
                                            const float* __restrict__ wT,
                                            short* __restrict__ Cb) {
  int v = blockIdx.x * 256 + threadIdx.x;   // 27*256 = 6912
  int jk = blockIdx.y;                       // 0..511
  float val = 0.f;
  if (jk < NJK && v < NV) {
    int j = jk / NJNT, k = jk - j * NJNT;
    val = jrT[j * NV + v] * wT[k * NV + v];
  }
  Cb[(size_t)jk * KPAD + v] = f2bf(val);
}

// ---- Pb[row][KPAD] bf16: rows 0..620 pdirs, 621..650 sdirs, 651..653 vtmpl, 654 ones, rest 0
__global__ void __launch_bounds__(256) k_Pm(const float* __restrict__ pdirs,
                                            const float* __restrict__ sdirs,
                                            const float* __restrict__ vtmpl,
                                            short* __restrict__ Pb) {
  int v = blockIdx.y * 256 + threadIdx.x;
  int r = blockIdx.x;                        // 0..703
  float val = 0.f;
  if (v < NV) {
    if (r < 621) {
      int m = r / 3, q = r - m * 3;
      val = pdirs[(size_t)m * N3 + v * 3 + q];
    } else if (r < 651) {
      int rr = r - 621; int m = rr / 3, q = rr - m * 3;
      val = sdirs[(size_t)m * N3 + v * 3 + q];
    } else if (r < 654) {
      val = vtmpl[v * 3 + (r - 651)];
    } else if (r == 654) {
      val = 1.0f;
    }
  }
  Pb[(size_t)r * KPAD + v] = f2bf(val);
}

// ---- MFMA GEMM: Dpart[z][m][n] = sum_{k in chunk z} P[m][k] * C[n][k] ----
// 64x64 tile, BK=64, 4 waves each own 16(M)x64(N). XOR-swizzled LDS (g ^= row&7).
__global__ void __launch_bounds__(256) k_gemm(const short* __restrict__ Pb,
                                              const short* __restrict__ Cb,
                                              float* __restrict__ Dpart) {
  int m0 = blockIdx.x * 64;   // 11
  int n0 = blockIdx.y * 64;   // 8
  int kb0 = blockIdx.z * KCH; // 12
  __shared__ __align__(16) short As[64 * 64];
  __shared__ __align__(16) short Bs[64 * 64];
  int t = threadIdx.x;
  int wid = t >> 6, lane = t & 63;
  int frow = wid * 16 + (lane & 15);
  int fgrp = lane >> 4;             // 0..3
  fx4 acc[4];
#pragma unroll
  for (int j = 0; j < 4; ++j)
#pragma unroll
    for (int r = 0; r < 4; ++r) acc[j][r] = 0.f;

  // staging indices: chunk c -> row=c>>3, g=c&7 (16B each)
  int c0 = t, c1 = t + 256;
  int row0 = c0 >> 3, g0 = c0 & 7, sw0 = g0 ^ (row0 & 7);
  int row1 = c1 >> 3, g1 = c1 & 7, sw1 = g1 ^ (row1 & 7);

  for (int kk = 0; kk < KCH / 64; ++kk) {
    int kb = kb0 + kk * 64;
    *(bfx8*)(As + row0 * 64 + sw0 * 8) = *(const bfx8*)(Pb + (size_t)(m0 + row0) * KPAD + kb + g0 * 8);
    *(bfx8*)(As + row1 * 64 + sw1 * 8) = *(const bfx8*)(Pb + (size_t)(m0 + row1) * KPAD + kb + g1 * 8);
    *(bfx8*)(Bs + row0 * 64 + sw0 * 8) = *(const bfx8*)(Cb + (size_t)(n0 + row0) * KPAD + kb + g0 * 8);
    *(bfx8*)(Bs + row1 * 64 + sw1 * 8) = *(const bfx8*)(Cb + (size_t)(n0 + row1) * KPAD + kb + g1 * 8);
    __syncthreads();
#pragma unroll
    for (int ks = 0; ks < 2; ++ks) {
      int ga = ks * 4 + fgrp;
      bfx8 a = *(const bfx8*)(As + frow * 64 + (ga ^ (frow & 7)) * 8);
#pragma unroll
      for (int j = 0; j < 4; ++j) {
        int bcol = j * 16 + (lane & 15);
        bfx8 b = *(const bfx8*)(Bs + bcol * 64 + (ga ^ (bcol & 7)) * 8);
        acc[j] = __builtin_amdgcn_mfma_f32_16x16x32_bf16(a, b, acc[j], 0, 0, 0);
      }
    }
    __syncthreads();
  }
  // C/D layout: col = lane&15 (within 16-tile), row = (lane>>4)*4 + reg
  float* dst = Dpart + (size_t)blockIdx.z * PROWSP * NJKP
             + (size_t)(m0 + wid * 16 + (lane >> 4) * 4) * NJKP + n0 + (lane & 15);
#pragma unroll
  for (int j = 0; j < 4; ++j)
#pragma unroll
    for (int r = 0; r < 4; ++r)
      dst[(size_t)r * NJKP + j * 16] = acc[j][r];
}

// ---- reduce K-split partials ----
__global__ void k_redD(const float* __restrict__ Dpart, float* __restrict__ D) {
  int i = blockIdx.x * 256 + threadIdx.x;
  if (i >= PROWSP * NJKP) return;
  float s = 0.f;
#pragma unroll
  for (int z = 0; z < KSPLIT; ++z) s += Dpart[(size_t)z * PROWSP * NJKP + i];
  D[i] = s;
}

// ---- SJ[k][j][c] for J reassociation (k==10 row = v_template) ----
__global__ void __launch_bounds__(256) k_SJ(const float* __restrict__ Jreg,
                                            const float* __restrict__ sdirs,
                                            const float* __restrict__ vtmpl,
                                            float* __restrict__ SJ) {
  int j = blockIdx.x, k = blockIdx.y, tid = threadIdx.x;
  const float* src = (k < NBETA) ? (sdirs + (size_t)k * N3) : vtmpl;
  float a0 = 0.f, a1 = 0.f, a2 = 0.f;
  for (int v = tid; v < NV; v += 256) {
    float w = Jreg[v * NJNT + j];
    a0 += w * src[v * 3 + 0];
    a1 += w * src[v * 3 + 1];
    a2 += w * src[v * 3 + 2];
  }
  __shared__ float red[4][3];
  int lane = tid & 63, wid = tid >> 6;
#pragma unroll
  for (int s = 1; s < 64; s <<= 1) {
    a0 += __shfl_xor(a0, s); a1 += __shfl_xor(a1, s); a2 += __shfl_xor(a2, s);
  }
  if (lane == 0) { red[wid][0] = a0; red[wid][1] = a1; red[wid][2] = a2; }
  __syncthreads();
  if (tid == 0) {
    float* o = SJ + (k * NJNT + j) * 3;
    o[0] = red[0][0] + red[1][0] + red[2][0] + red[3][0];
    o[1] = red[0][1] + red[1][1] + red[2][1] + red[3][1];
    o[2] = red[0][2] + red[1][2] + red[2][2] + red[3][2];
  }
}

__global__ void k_Jsmall(const float* __restrict__ beta, const float* __restrict__ SJ,
                         float* __restrict__ J) {
  int idx = blockIdx.x * 256 + threadIdx.x;
  if (idx >= NBATCH * 72) return;
  int b = idx / 72, r = idx - b * 72;
  float acc = SJ[NBETA * 72 + r];
  const float* bb = beta + b * NBETA;
#pragma unroll
  for (int k = 0; k < NBETA; ++k) acc += bb[k] * SJ[k * 72 + r];
  J[idx] = acc;
}

// ---- Rodrigues: Rs[b][24][9] and pfc[b][224] = [pf 207 | beta 10 | 1 | pad] ----
__global__ void k_rod(const float* __restrict__ theta, const float* __restrict__ beta,
                      float* __restrict__ Rs, float* __restrict__ pfc) {
  int b = blockIdx.x * 64 + threadIdx.x;
  if (b >= NBATCH) return;
  for (int j = 0; j < NJNT; ++j) {
    float a0 = theta[b * 72 + j * 3 + 0];
    float a1 = theta[b * 72 + j * 3 + 1];
    float a2 = theta[b * 72 + j * 3 + 2];
    float e0 = a0 + 1e-8f, e1 = a1 + 1e-8f, e2 = a2 + 1e-8f;
    float ang = sqrtf(e0 * e0 + e1 * e1 + e2 * e2);
    float inv = 1.0f / ang;
    float h = 0.5f * ang;
    float w = cosf(h), s = sinf(h);
    float x = a0 * inv * s, y = a1 * inv * s, z = a2 * inv * s;
    float R[9];
    R[0] = w*w + x*x - y*y - z*z; R[1] = 2.f*(x*y - w*z); R[2] = 2.f*(x*z + w*y);
    R[3] = 2.f*(x*y + w*z); R[4] = w*w - x*x + y*y - z*z; R[5] = 2.f*(y*z - w*x);
    R[6] = 2.f*(x*z - w*y); R[7] = 2.f*(y*z + w*x); R[8] = w*w - x*x - y*y + z*z;
#pragma unroll
    for (int r = 0; r < 9; ++r) Rs[b * 216 + j * 9 + r] = R[r];
    if (j >= 1) {
#pragma unroll
      for (int r = 0; r < 9; ++r)
        pfc[b * CSTR + (j - 1) * 9 + r] = R[r] - ((r % 4 == 0) ? 1.0f : 0.0f);
    }
  }
#pragma unroll
  for (int i = 0; i < NBETA; ++i) pfc[b * CSTR + NPF + i] = beta[b * NBETA + i];
  pfc[b * CSTR + NPF + NBETA] = 1.0f;
}

// ---- kinematic chain: A[b][24][12] ----
__global__ void k_chain(const float* __restrict__ Rs, const float* __restrict__ Jin,
                        float* __restrict__ A) {
  int b = blockIdx.x * 64 + threadIdx.x;
  if (b >= NBATCH) return;
  const float* Jb = Jin + b * 72;
  const float* Rb = Rs + b * 216;
  float* Ab = A + b * 288;
#pragma unroll
  for (int r = 0; r < 3; ++r) {
#pragma unroll
    for (int c = 0; c < 3; ++c) Ab[r * 4 + c] = Rb[r * 3 + c];
    Ab[r * 4 + 3] = Jb[r];
  }
  for (int i = 1; i < NJNT; ++i) {
    int p = d_par[i];
    const float* P = Ab + p * 12;
    const float* R = Rb + i * 9;
    float t0 = Jb[i * 3 + 0] - Jb[p * 3 + 0];
    float t1 = Jb[i * 3 + 1] - Jb[p * 3 + 1];
    float t2 = Jb[i * 3 + 2] - Jb[p * 3 + 2];
    float* O = Ab + i * 12;
#pragma unroll
    for (int r = 0; r < 3; ++r) {
      float p0 = P[r * 4 + 0], p1 = P[r * 4 + 1], p2 = P[r * 4 + 2], p3 = P[r * 4 + 3];
#pragma unroll
      for (int c = 0; c < 3; ++c)
        O[r * 4 + c] = p0 * R[0 + c] + p1 * R[3 + c] + p2 * R[6 + c];
      O[r * 4 + 3] = p0 * t0 + p1 * t1 + p2 * t2 + p3;
    }
  }
  for (int i = 0; i < NJNT; ++i) {
    float jx = Jb[i * 3 + 0], jy = Jb[i * 3 + 1], jz = Jb[i * 3 + 2];
    float* O = Ab + i * 12;
#pragma unroll
    for (int r = 0; r < 3; ++r)
      O[r * 4 + 3] -= O[r * 4 + 0] * jx + O[r * 4 + 1] * jy + O[r * 4 + 2] * jz;
  }
}

// ---- S[b][jk][q] = sum_r coef[b][r] * D[3r+q][jk]; BCH batches per block ----
__global__ void __launch_bounds__(512) k_S(const float* __restrict__ D,
                                           const float* __restrict__ pfc,
                                           float* __restrict__ S) {
  int jk = threadIdx.x;
  int b0 = blockIdx.x * BCH;
  if (jk >= NJK) return;
  float acc[BCH][3];
#pragma unroll
  for (int i = 0; i < BCH; ++i)
#pragma unroll
    for (int q = 0; q < 3; ++q) acc[i][q] = 0.f;
#pragma unroll 2
  for (int r = 0; r < NCOEF; ++r) {
    float d0 = D[(size_t)(3 * r + 0) * NJKP + jk];
    float d1 = D[(size_t)(3 * r + 1) * NJKP + jk];
    float d2 = D[(size_t)(3 * r + 2) * NJKP + jk];
#pragma unroll
    for (int i = 0; i < BCH; ++i) {
      float c = pfc[(b0 + i) * CSTR + r];  // uniform -> s_load
      acc[i][0] += c * d0;
      acc[i][1] += c * d1;
      acc[i][2] += c * d2;
    }
  }
#pragma unroll
  for (int i = 0; i < BCH; ++i) {
    float* o = S + ((size_t)(b0 + i) * NJK + jk) * 3;
    o[0] = acc[i][0]; o[1] = acc[i][1]; o[2] = acc[i][2];
  }
}

// ---- joints[b,j,c] = sum_k A[b,k,c,:] . [S[b,jk,0..2], c0[jk]] ----
__global__ void k_final(const float* __restrict__ S, const float* __restrict__ D,
                        const float* __restrict__ A, float* __restrict__ out) {
  int idx = blockIdx.x * 256 + threadIdx.x;
  if (idx >= NBATCH * NJO * 3) return;
  int b = idx / 57, r = idx - b * 57;
  int j = r / 3, c = r - j * 3;
  const float* c0 = D + (size_t)654 * NJKP + j * NJNT;
  float acc = 0.f;
#pragma unroll
  for (int k = 0; k < NJNT; ++k) {
    const float* Ar = A + b * 288 + k * 12 + c * 4;
    const float* Sr = S + ((size_t)b * NJK + j * NJNT + k) * 3;
    acc += Ar[0] * Sr[0] + Ar[1] * Sr[1] + Ar[2] * Sr[2] + Ar[3] * c0[k];
  }
  out[idx] = acc;
}

extern "C" void kernel_launch(void* const* d_in, const int* in_sizes, int n_in,
                              void* d_out, int out_size, void* d_ws, size_t ws_size,
                              hipStream_t stream) {
  const float* beta  = (const float*)d_in[0];
  const float* theta = (const float*)d_in[1];
  const float* vtmpl = (const float*)d_in[2];
  const float* sdirs = (const float*)d_in[3];
  const float* Jreg  = (const float*)d_in[4];
  const float* pdirs = (const float*)d_in[5];
  const float* lbs   = (const float*)d_in[6];
  const float* jreg2 = (const float*)d_in[7];
  float* out = (float*)d_out;

  float* ws    = (float*)d_ws;
  short* Cb    = (short*)ws;                              // 512*6912 bf16  = 7.1MB
  short* Pb    = Cb + (size_t)NJKP * KPAD;                // 704*6912 bf16  = 9.7MB
  float* Dpart = (float*)(Pb + (size_t)PROWSP * KPAD);    // 12*704*512 f32 = 17.3MB
  float* D     = Dpart + (size_t)KSPLIT * PROWSP * NJKP;  // 704*512
  float* S     = D     + (size_t)PROWSP * NJKP;           // 512*456*3
  float* pfc   = S     + (size_t)NBATCH * NJK * 3;        // 512*224
  float* Rs    = pfc   + (size_t)NBATCH * CSTR;           // 512*216
  float* Jout  = Rs    + (size_t)NBATCH * 216;            // 512*72
  float* A     = Jout  + (size_t)NBATCH * 72;             // 512*288
  float* jrT   = A     + (size_t)NBATCH * 288;            // 19*6890
  float* wT    = jrT   + (size_t)NJO * NV;                // 24*6890
  float* SJ    = wT    + (size_t)NJNT * NV;               // 11*72

  k_tr<<<dim3((NV * NJNT + 255) / 256), 256, 0, stream>>>(jreg2, lbs, jrT, wT);
  k_rod<<<dim3(8), 64, 0, stream>>>(theta, beta, Rs, pfc);
  k_SJ<<<dim3(NJNT, NBETA + 1), 256, 0, stream>>>(Jreg, sdirs, vtmpl, SJ);
  k_Jsmall<<<dim3((NBATCH * 72 + 255) / 256), 256, 0, stream>>>(beta, SJ, Jout);
  k_chain<<<dim3(8), 64, 0, stream>>>(Rs, Jout, A);
  k_Cm<<<dim3(KPAD / 256, NJKP), 256, 0, stream>>>(jrT, wT, Cb);
  k_Pm<<<dim3(PROWSP, KPAD / 256), 256, 0, stream>>>(pdirs, sdirs, vtmpl, Pb);
  k_gemm<<<dim3(PROWSP / 64, NJKP / 64, KSPLIT), 256, 0, stream>>>(Pb, Cb, Dpart);
  k_redD<<<dim3((PROWSP * NJKP + 255) / 256), 256, 0, stream>>>(Dpart, D);
  k_S<<<dim3(NBATCH / BCH), 512, 0, stream>>>(D, pfc, S);
  k_final<<<dim3((NBATCH * NJO * 3 + 255) / 256), 256, 0, stream>>>(S, D, A, out);
}